// Round 15
// baseline (1037.861 us; speedup 1.0000x reference)
//
#include <hip/hip_runtime.h>
#include <math.h>

constexpr int NB = 32;      // batches
constexpr int NP = 1024;    // points per batch
constexpr int NK = 10;      // k nearest (includes self)
constexpr int BN = NB * NP;
constexpr int NT = NP/128;  // m-tiles per row = 8
constexpr int NSLOT = 1024; // partial-reduction slots for PairNorm stats

__device__ __forceinline__ float4 ld4(const float* p){ return *reinterpret_cast<const float4*>(p); }
__device__ __forceinline__ float2 ld2(const float* p){ return *reinterpret_cast<const float2*>(p); }
__device__ __forceinline__ void st4(float* p, float4 v){ *reinterpret_cast<float4*>(p) = v; }

// ---------------- pre-transpose W into WT[n][k] (n in [0,2*DOUT)) ----------------
template<int DIN, int DOUT>
__global__ void k_wt(const float* __restrict__ W, float* __restrict__ WT){
  int n = blockIdx.x, k = threadIdx.x;
  float v = (n < DOUT) ? W[(size_t)k*DOUT + n]
                       : W[(size_t)DIN*DOUT + (size_t)k*DOUT + (n - DOUT)];
  WT[(size_t)n*DIN + k] = v;
}

// ---------------- per-tile top-NK selection epilogue (row-interleaved) ----------------
// Lex (v, col), strict < == lax.top_k lowest-index tie-break. 8 rows interleaved
// per shuffle step (8x ILP); lane rx==sel banks winners; one 80B write/row at end.
// Round-13 lesson: the symmetric both-direction variant cost more than it saved
// (VGPR 68->96, occupancy 30->16.6%) -- keep row-only.
__device__ __forceinline__ void sel_rows(float (&d)[8][8], int rx, int m0, float2* c0){
  float kv[8]; int kc[8];
#pragma unroll
  for (int k=0;k<8;++k){ kv[k] = 0.f; kc[k] = 0; }
#pragma unroll 1
  for (int sel=0; sel<NK; ++sel){
    float v[8]; int c[8];
#pragma unroll
    for (int k=0;k<8;++k){
      v[k] = d[k][0]; c[k] = rx*8;
#pragma unroll
      for (int l=1;l<8;++l){
        int cc = rx*8+l;
        if (d[k][l] < v[k]){ v[k] = d[k][l]; c[k] = cc; }
      }
    }
#pragma unroll
    for (int off=1; off<16; off<<=1){
#pragma unroll
      for (int k=0;k<8;++k){
        float ov = __shfl_xor(v[k], off, 64);
        int   oc = __shfl_xor(c[k], off, 64);
        if (ov < v[k] || (ov == v[k] && oc < c[k])){ v[k] = ov; c[k] = oc; }
      }
    }
#pragma unroll
    for (int k=0;k<8;++k){
      if (rx == (c[k]>>3)){
#pragma unroll
        for (int l=0;l<8;++l) if (l == (c[k]&7)) d[k][l] = __builtin_inff();
      }
    }
    if (rx == sel){
#pragma unroll
      for (int k=0;k<8;++k){ kv[k] = v[k]; kc[k] = c[k]; }
    }
  }
  if (rx < NK){
#pragma unroll
    for (int k=0;k<8;++k)
      c0[(size_t)k*(NT*NK) + rx] = make_float2(kv[k], (float)(m0 + kc[k]));
  }
}

// ---------------- per-wave candidate merge: 80 -> NK indices into idx_s ----------------
// Verbatim semantics of the old k_merge kernel (validated rounds 9-14): lex
// (v, idx) reduce over 64+16 lanes, invalidate-by-index, lane 0 writes.
// Each wave merges rows w*8 .. w*8+7 of the block's 32 points serially; the
// serial cost (~2900 ops/wave) hides under the caller's subsequent memory phase.
__device__ __forceinline__ void merge_rows(const float2* __restrict__ cand,
    size_t p0, int* idx_s){
  int lane = threadIdx.x & 63, w = threadIdx.x >> 6;
#pragma unroll 1
  for (int t=0; t<8; ++t){
    int pl = w*8 + t;
    const float2* cr = cand + (p0 + pl)*(size_t)(NT*NK);
    float2 e0 = cr[lane];
    float v0 = e0.x; int c0 = (int)e0.y;
    float v1; int c1;
    if (lane < NT*NK - 64){ float2 e1 = cr[64+lane]; v1 = e1.x; c1 = (int)e1.y; }
    else { v1 = __builtin_inff(); c1 = 0x7fffffff; }
#pragma unroll 1
    for (int sel=0; sel<NK; ++sel){
      float v; int c;
      if (v1 < v0 || (v1 == v0 && c1 < c0)){ v = v1; c = c1; } else { v = v0; c = c0; }
#pragma unroll
      for (int off=1; off<64; off<<=1){
        float ov = __shfl_xor(v, off, 64);
        int   oc = __shfl_xor(c, off, 64);
        if (ov < v || (ov == v && oc < c)){ v = ov; c = oc; }
      }
      if (c0 == c) v0 = __builtin_inff();
      if (c1 == c) v1 = __builtin_inff();
      if (lane == 0) idx_s[pl*NK + sel] = c;
    }
  }
}

// ---------------- fused kNN, DIN=2 (layer 1; sq computed inline) ----------------
__global__ __launch_bounds__(256) void k_knn2(const float* __restrict__ x,
    float2* __restrict__ cand){
  int b = blockIdx.z;
  int n0 = blockIdx.x*128, m0 = blockIdx.y*128;
  int ry = threadIdx.x>>4, rx = threadIdx.x&15;
  const float* xb = x + (size_t)b*NP*2;
  float2 av[8], bv[8]; float sn[8], sm[8];
#pragma unroll
  for (int k=0;k<8;++k){
    av[k] = ld2(xb + (size_t)(n0+ry*8+k)*2);
    bv[k] = ld2(xb + (size_t)(m0+rx*8+k)*2);
    sn[k] = av[k].x*av[k].x + av[k].y*av[k].y;   // == old k_sq_pos expression
    sm[k] = bv[k].x*bv[k].x + bv[k].y*bv[k].y;
  }
  float d[8][8];
#pragma unroll
  for (int k=0;k<8;++k)
#pragma unroll
    for (int l=0;l<8;++l){
      float dot = av[k].x*bv[l].x + av[k].y*bv[l].y;
      d[k][l] = (sn[k] + sm[l]) - 2.f*dot;
    }
  sel_rows(d, rx, m0, cand + (((size_t)b*NP + n0 + ry*8)*NT + blockIdx.y)*NK);
}

// ---------------- fused kNN, DIN in {64,128}: K4p=8 phased GEMM + select ----------------
// FIXED 32KB LDS (2 x 128 x 8 f4): DIN=64 -> 2 phases, DIN=128 -> 4 phases.
// 32KB -> 4-5 blocks/CU (round 12: occupancy 30%, VALUBusy 70%). 64KB was
// 2 waves/SIMD and latency-bound (round 11: 306us). Rolled staging (lean
// idiom); register staging spilled in rounds 5-8 -- keep it rolled.
template<int DIN>
__global__ __launch_bounds__(256) void k_knn(const float* __restrict__ x,
    const float* __restrict__ sq, float2* __restrict__ cand){
  constexpr int K4 = DIN/4, K4p = 8, NPH = K4/K4p, MASK = K4p-1;
  extern __shared__ float4 smem[];
  float4* as4 = smem;            // 128*K4p
  float4* bs4 = smem + 128*K4p;  // 128*K4p
  int b = blockIdx.z;
  int n0 = blockIdx.x*128, m0 = blockIdx.y*128;
  int ry = threadIdx.x>>4, rx = threadIdx.x&15;
  const float* xb = x + (size_t)b*NP*DIN;
  float acc[8][8];
#pragma unroll
  for (int k=0;k<8;++k)
#pragma unroll
    for (int l=0;l<8;++l) acc[k][l] = 0.f;
#pragma unroll 1
  for (int ph=0; ph<NPH; ++ph){
    __syncthreads();                       // previous phase reads done
    for (int u=threadIdx.x; u<128*K4p; u+=256){
      int r = u >> 3, c = u & 7;
      int sw = r*K4p + ((c + (r>>3)) & MASK);
      as4[sw] = ld4(xb + (size_t)(n0+r)*DIN + 4*(ph*K4p + c));
      bs4[sw] = ld4(xb + (size_t)(m0+r)*DIN + 4*(ph*K4p + c));
    }
    __syncthreads();                       // staged data visible
#pragma unroll 2
    for (int d4=0; d4<K4p; ++d4){
      float4 a_[8], b_[8];
#pragma unroll
      for (int k=0;k<8;++k) a_[k] = as4[(ry*8+k)*K4p + ((d4 + ry) & MASK)];
#pragma unroll
      for (int l=0;l<8;++l) b_[l] = bs4[(rx*8+l)*K4p + ((d4 + rx) & MASK)];
#pragma unroll
      for (int k=0;k<8;++k)
#pragma unroll
        for (int l=0;l<8;++l)
          acc[k][l] += a_[k].x*b_[l].x + a_[k].y*b_[l].y + a_[k].z*b_[l].z + a_[k].w*b_[l].w;
    }
  }
  const float* sqb = sq + (size_t)b*NP;
  float sn[8], sm[8];
#pragma unroll
  for (int k=0;k<8;++k){ sn[k] = sqb[n0+ry*8+k]; sm[k] = sqb[m0+rx*8+k]; }
#pragma unroll
  for (int k=0;k<8;++k)
#pragma unroll
    for (int l=0;l<8;++l) acc[k][l] = (sn[k]+sm[l]) - 2.f*acc[k][l];
  sel_rows(acc, rx, m0, cand + (((size_t)b*NP + n0 + ry*8)*NT + blockIdx.y)*NK);
}

// ---------------- GEMM: xcat = x @ WT^T, K4p=8 phases, pre-transposed W ----------------
template<int DIN, int DOUT>
__global__ __launch_bounds__(256) void k_gemm(const float* __restrict__ x,
    const float* __restrict__ WT, float* __restrict__ xcat, int m_base){
  constexpr int K4 = DIN/4, K4p = 8, NPH = K4/K4p, MASK = K4p-1;
  extern __shared__ float4 smem[];
  float4* as4 = smem;            // 128*K4p
  float4* bs4 = smem + 128*K4p;  // 128*K4p
  int m0 = blockIdx.x*128;                 // local row tile
  int nc = blockIdx.y*128;                 // output col tile in [0, 2*DOUT)
  const float* xg = x + (size_t)(m_base + m0)*DIN;
  const float* Bg = WT + (size_t)nc*DIN;
  int ry = threadIdx.x>>4, rx = threadIdx.x&15;
  float acc[8][8];
#pragma unroll
  for (int k=0;k<8;++k)
#pragma unroll
    for (int l=0;l<8;++l) acc[k][l] = 0.f;
#pragma unroll 1
  for (int ph=0; ph<NPH; ++ph){
    __syncthreads();
    for (int u=threadIdx.x; u<128*K4p; u+=256){
      int r = u >> 3, c = u & 7;
      int sw = r*K4p + ((c + (r>>3)) & MASK);
      as4[sw] = ld4(xg + (size_t)r*DIN + 4*(ph*K4p + c));
      bs4[sw] = ld4(Bg + (size_t)r*DIN + 4*(ph*K4p + c));
    }
    __syncthreads();
#pragma unroll 2
    for (int d4=0; d4<K4p; ++d4){
      float4 a_[8], b_[8];
#pragma unroll
      for (int k=0;k<8;++k) a_[k] = as4[(ry*8+k)*K4p + ((d4 + ry) & MASK)];
#pragma unroll
      for (int l=0;l<8;++l) b_[l] = bs4[(rx*8+l)*K4p + ((d4 + rx) & MASK)];
#pragma unroll
      for (int k=0;k<8;++k)
#pragma unroll
        for (int l=0;l<8;++l)
          acc[k][l] += a_[k].x*b_[l].x + a_[k].y*b_[l].y + a_[k].z*b_[l].z + a_[k].w*b_[l].w;
    }
  }
  float* outb = xcat + (size_t)(m0 + ry*8)*(2*DOUT) + nc + rx*8;
#pragma unroll
  for (int k=0;k<8;++k){
    st4(outb + (size_t)k*(2*DOUT),     make_float4(acc[k][0],acc[k][1],acc[k][2],acc[k][3]));
    st4(outb + (size_t)k*(2*DOUT) + 4, make_float4(acc[k][4],acc[k][5],acc[k][6],acc[k][7]));
  }
}

// ---------------- gather-max epilogue: h = relu(z + b - y_self + max_j y_j) ----------------
// Now merges its own 32 rows' candidates (merge_rows) instead of reading a
// precomputed idx buffer -- deletes the k_merge dispatches + idx round-trip.
template<int DOUT>
__global__ __launch_bounds__(256) void k_gmax(const float* __restrict__ xcat,
    const float2* __restrict__ cand, const float* __restrict__ bias,
    float* __restrict__ hout, float* __restrict__ spart, int p_base, int slot_base){
  constexpr int TP = DOUT/4;        // threads per point
  constexpr int ROWS = 256/TP;      // points in flight
  constexpr int PPT = 32/ROWS;      // points per thread
  __shared__ int idx_s[32*NK];
  __shared__ float red[1024];       // ROWS*DOUT == 1024 floats
  __shared__ float ssp[4];
  int c4 = threadIdx.x % TP, pr = threadIdx.x / TP;
  int c = 4*c4;
  int p0 = blockIdx.x*32 + p_base;          // global first point of block
  merge_rows(cand, (size_t)p0, idx_s);
  __syncthreads();
  float4 b4 = ld4(bias + c);
  float4 fsum = make_float4(0.f,0.f,0.f,0.f);
  float ss = 0.f;
  int pbl = (((p0 - p_base) >> 10) << 10);  // local batch base row
#pragma unroll
  for (int t=0; t<PPT; ++t){
    int pl = pr + t*ROWS;
    int lrow = (p0 - p_base) + pl;
    const float* row = xcat + (size_t)lrow*(2*DOUT);
    float4 z = ld4(row + c), ys = ld4(row + DOUT + c);
    float4 mv = make_float4(-__builtin_inff(),-__builtin_inff(),-__builtin_inff(),-__builtin_inff());
    for (int j=0;j<NK;++j){
      int q = pbl + idx_s[pl*NK + j];
      float4 g = ld4(xcat + (size_t)q*(2*DOUT) + DOUT + c);
      mv.x = fmaxf(mv.x, g.x); mv.y = fmaxf(mv.y, g.y);
      mv.z = fmaxf(mv.z, g.z); mv.w = fmaxf(mv.w, g.w);
    }
    float4 v;
    v.x = fmaxf(z.x + b4.x - ys.x + mv.x, 0.f);
    v.y = fmaxf(z.y + b4.y - ys.y + mv.y, 0.f);
    v.z = fmaxf(z.z + b4.z - ys.z + mv.z, 0.f);
    v.w = fmaxf(z.w + b4.w - ys.w + mv.w, 0.f);
    st4(hout + (size_t)(p0 + pl)*DOUT + c, v);
    fsum.x += v.x; fsum.y += v.y; fsum.z += v.z; fsum.w += v.w;
    ss += v.x*v.x + v.y*v.y + v.z*v.z + v.w*v.w;
  }
  st4(&red[pr*DOUT + c], fsum);
#pragma unroll
  for (int off=32; off; off>>=1) ss += __shfl_xor(ss, off, 64);
  if ((threadIdx.x&63)==0) ssp[threadIdx.x>>6] = ss;
  __syncthreads();
  int slot = slot_base + blockIdx.x;
  for (int o=threadIdx.x; o<DOUT; o+=256){
    float s = 0.f;
#pragma unroll
    for (int r=0;r<ROWS;++r) s += red[r*DOUT + o];
    spart[(size_t)o*NSLOT + slot] = s;
  }
  if (threadIdx.x==0) spart[(size_t)DOUT*NSLOT + slot] = ssp[0]+ssp[1]+ssp[2]+ssp[3];
}

// ---------------- edge conv layer 1 (din=2, dout=64; merges own candidates) ----------------
__global__ __launch_bounds__(256) void k_edge1(const float* __restrict__ x,
    const float2* __restrict__ cand, const float* __restrict__ W,
    const float* __restrict__ bias, float* __restrict__ hout,
    float* __restrict__ spart){
  __shared__ int idx_s[32*NK];
  __shared__ float red[4][64];
  __shared__ float ssw[4];
  int lane = threadIdx.x & 63, wv = threadIdx.x >> 6;
  int p0 = blockIdx.x * 32;
  int b = p0 >> 10;
  int pl0 = p0 & 1023;
  const float* xb = x + ((size_t)b<<10)*2;
  merge_rows(cand, (size_t)p0, idx_s);
  __syncthreads();
  float w0=W[lane], w1=W[64+lane], w2=W[128+lane], w3=W[192+lane];
  float bi = bias[lane];
  float fsum = 0.f, ss = 0.f;
#pragma unroll
  for (int t=0;t<8;++t){
    int pl = wv*8 + t;
    float2 xi = ld2(xb + (size_t)(pl0+pl)*2);
    float common = xi.x*w0 + xi.y*w1 + bi;
    float mv = -__builtin_inff();
    for (int j=0;j<NK;++j){
      float2 xj = ld2(xb + (size_t)idx_s[pl*NK+j]*2);
      mv = fmaxf(mv, (xj.x-xi.x)*w2 + (xj.y-xi.y)*w3);
    }
    float v = fmaxf(common + mv, 0.f);
    hout[(size_t)(p0+pl)*64 + lane] = v;
    fsum += v; ss += v*v;
  }
  red[wv][lane] = fsum;
#pragma unroll
  for (int off=32; off; off>>=1) ss += __shfl_xor(ss, off, 64);
  if (lane==0) ssw[wv] = ss;
  __syncthreads();
  if (threadIdx.x < 64){
    float s = red[0][lane]+red[1][lane]+red[2][lane]+red[3][lane];
    spart[(size_t)lane*NSLOT + blockIdx.x] = s;
  }
  if (threadIdx.x==0) spart[(size_t)64*NSLOT + blockIdx.x] = ssw[0]+ssw[1]+ssw[2]+ssw[3];
}

// ---------------- finalize PairNorm stats from partials ----------------
template<int DOUT>
__global__ __launch_bounds__(256) void k_finalize2(const float* __restrict__ spart,
    float* __restrict__ stats){
  __shared__ float part[4];
  __shared__ float ssh;
  float musq = 0.f;
  for (int f = threadIdx.x; f <= DOUT; f += 256){
    const float* row = spart + (size_t)f*NSLOT;
    float4 a = make_float4(0.f,0.f,0.f,0.f);
    for (int s=0; s<NSLOT; s+=4){
      float4 v = ld4(row + s);
      a.x += v.x; a.y += v.y; a.z += v.z; a.w += v.w;
    }
    float s = (a.x + a.y) + (a.z + a.w);
    if (f < DOUT){
      float m = s * (1.f/BN);
      stats[320+f] = m;
      musq += m*m;
    } else {
      ssh = s;
    }
  }
#pragma unroll
  for (int off=32; off; off>>=1) musq += __shfl_xor(musq, off, 64);
  if ((threadIdx.x&63)==0) part[threadIdx.x>>6] = musq;
  __syncthreads();
  if (threadIdx.x==0){
    float mu2 = part[0]+part[1]+part[2]+part[3];
    float msn = ssh*(1.f/BN) - mu2;
    stats[576] = 1.f / sqrtf(1e-5f + msn);
  }
}

// ---------------- normalize in place + next-layer sq (wave per row) ----------------
template<int DOUT>
__global__ __launch_bounds__(256) void k_norm(float* __restrict__ h,
    const float* __restrict__ stats, float* __restrict__ sq){
  int lane = threadIdx.x&63, wv = threadIdx.x>>6;
  int row = blockIdx.x*4 + wv;
  float inv = stats[576];
  const float* mu = stats + 320;
  float* hr = h + (size_t)row*DOUT;
  float s = 0.f;
  if constexpr (DOUT == 64){
    float v = (hr[lane] - mu[lane]) * inv;
    hr[lane] = v;
    s = v*v;
  } else if constexpr (DOUT == 128){
    float2 x2 = ld2(hr + 2*lane), m2 = ld2(mu + 2*lane);
    float a = (x2.x - m2.x)*inv, b = (x2.y - m2.y)*inv;
    *reinterpret_cast<float2*>(hr + 2*lane) = make_float2(a,b);
    s = a*a + b*b;
  } else {
    float4 x4 = ld4(hr + 4*lane), m4 = ld4(mu + 4*lane);
    float4 v;
    v.x = (x4.x-m4.x)*inv; v.y = (x4.y-m4.y)*inv;
    v.z = (x4.z-m4.z)*inv; v.w = (x4.w-m4.w)*inv;
    st4(hr + 4*lane, v);
    s = v.x*v.x + v.y*v.y + v.z*v.z + v.w*v.w;
  }
#pragma unroll
  for (int off=32; off; off>>=1) s += __shfl_xor(s, off, 64);
  if (lane==0) sq[row] = s;
}

// ---------------- global max pool (partial) ----------------
__global__ __launch_bounds__(256) void k_pool1(const float* __restrict__ h, float* __restrict__ gpart){
  int b = blockIdx.x, c = blockIdx.y, o = threadIdx.x;
  const float* hp = h + ((size_t)b*NP + c*128)*256 + o;
  float m = -__builtin_inff();
  for (int n=0;n<128;++n) m = fmaxf(m, hp[(size_t)n*256]);
  gpart[((size_t)c*NB + b)*256 + o] = m;
}

// ---------------- pool finish + MLP head ----------------
__global__ __launch_bounds__(256) void k_head(const float* __restrict__ gpart,
    const float* __restrict__ Wl1, const float* __restrict__ bl1,
    const float* __restrict__ Wl2, const float* __restrict__ bl2,
    float* __restrict__ out){
  __shared__ float g_s[256];
  __shared__ float h_s[64];
  int b = blockIdx.x, t = threadIdx.x;
  float m = -__builtin_inff();
  for (int c=0;c<8;++c) m = fmaxf(m, gpart[((size_t)c*NB + b)*256 + t]);
  g_s[t] = m;
  __syncthreads();
  if (t < 64){
    float a = bl1[t];
    for (int k=0;k<256;++k) a += g_s[k]*Wl1[(size_t)k*64 + t];
    h_s[t] = fmaxf(a, 0.f);
  }
  __syncthreads();
  if (t < 2){
    float a = bl2[t];
    for (int i=0;i<64;++i) a += h_s[i]*Wl2[(size_t)i*2 + t];
    out[(size_t)b*2 + t] = a;
  }
}

extern "C" void kernel_launch(void* const* d_in, const int* in_sizes, int n_in,
                              void* d_out, int out_size, void* d_ws, size_t ws_size,
                              hipStream_t stream){
  (void)in_sizes; (void)n_in; (void)out_size; (void)ws_size;
  const float* pos = (const float*)d_in[0];
  const float* W1  = (const float*)d_in[1];
  const float* b1  = (const float*)d_in[2];
  const float* W2  = (const float*)d_in[3];
  const float* b2  = (const float*)d_in[4];
  const float* W3  = (const float*)d_in[5];
  const float* b3  = (const float*)d_in[6];
  const float* Wl1 = (const float*)d_in[7];
  const float* bl1 = (const float*)d_in[8];
  const float* Wl2 = (const float*)d_in[9];
  const float* bl2 = (const float*)d_in[10];
  float* outp = (float*)d_out;

  (void)hipFuncSetAttribute((const void*)k_knn<128>,       hipFuncAttributeMaxDynamicSharedMemorySize, 32768);
  (void)hipFuncSetAttribute((const void*)k_knn<64>,        hipFuncAttributeMaxDynamicSharedMemorySize, 32768);
  (void)hipFuncSetAttribute((const void*)k_gemm<128,256>,  hipFuncAttributeMaxDynamicSharedMemorySize, 32768);
  (void)hipFuncSetAttribute((const void*)k_gemm<64,128>,   hipFuncAttributeMaxDynamicSharedMemorySize, 32768);

  char* w = (char*)d_ws;
  size_t off = 0;
  auto take = [&](size_t bytes)->char*{ char* p = w + off; off += (bytes + 255) & ~(size_t)255; return p; };
  float*  sq    = (float*)take((size_t)BN*4);
  float*  x1    = (float*)take((size_t)BN*64*4);
  float*  x2    = (float*)take((size_t)BN*128*4);
  float*  x3    = (float*)take((size_t)BN*256*4);
  float*  stats = (float*)take(4096);
  float*  spart = (float*)take((size_t)257*NSLOT*4);   // feature-major partials
  float*  gpart = (float*)take((size_t)8*NB*256*4);
  float*  wt2   = (float*)take((size_t)256*64*4);      // W2 pre-transposed [n][k]
  float*  wt3   = (float*)take((size_t)512*128*4);     // W3 pre-transposed [n][k]
  float2* cand  = (float2*)take((size_t)BN*NT*NK*8);   // 21MB, own buffer (gmax reads it with xcat)
  float*  xcat  = (float*)take((size_t)BN*256*4);      // 32MB (layer3 runs in two halves)

  dim3 gknn(NP/128, NP/128, NB);

  // pre-transpose weights (tiny, once per call)
  k_wt<64,128><<<256, 64, 0, stream>>>(W2, wt2);
  k_wt<128,256><<<512, 128, 0, stream>>>(W3, wt3);

  // ---- layer 1 ----
  k_knn2<<<gknn, 256, 0, stream>>>(pos, cand);
  k_edge1<<<BN/32, 256, 0, stream>>>(pos, cand, W1, b1, x1, spart);
  k_finalize2<64><<<1, 256, 0, stream>>>(spart, stats);
  k_norm<64><<<BN/4, 256, 0, stream>>>(x1, stats, sq);

  // ---- layer 2 ----
  k_knn<64><<<gknn, 256, 32768, stream>>>(x1, sq, cand);
  k_gemm<64,128><<<dim3(BN/128, 2), 256, 32768, stream>>>(x1, wt2, xcat, 0);
  k_gmax<128><<<BN/32, 256, 0, stream>>>(xcat, cand, b2, x2, spart, 0, 0);
  k_finalize2<128><<<1, 256, 0, stream>>>(spart, stats);
  k_norm<128><<<BN/4, 256, 0, stream>>>(x2, stats, sq);

  // ---- layer 3 (two halves: xcat is 32MB) ----
  k_knn<128><<<gknn, 256, 32768, stream>>>(x2, sq, cand);
  for (int h=0; h<2; ++h){
    int m_base = h * (BN/2);
    k_gemm<128,256><<<dim3(BN/2/128, 4), 256, 32768, stream>>>(x2, wt3, xcat, m_base);
    k_gmax<256><<<BN/2/32, 256, 0, stream>>>(xcat, cand, b3, x3, spart, m_base, h*(BN/2/32));
  }
  k_finalize2<256><<<1, 256, 0, stream>>>(spart, stats);
  k_norm<256><<<BN/4, 256, 0, stream>>>(x3, stats, sq);

  // ---- pool + head ----
  k_pool1<<<dim3(NB, 8), 256, 0, stream>>>(x3, gpart);
  k_head<<<NB, 256, 0, stream>>>(gpart, Wl1, bl1, Wl2, bl2, outp);
}

// Round 16
// 943.605 us; speedup vs baseline: 1.0999x; 1.0999x over previous
//
#include <hip/hip_runtime.h>
#include <math.h>

constexpr int NB = 32;      // batches
constexpr int NP = 1024;    // points per batch
constexpr int NK = 10;      // k nearest (includes self)
constexpr int BN = NB * NP;
constexpr int NT = NP/128;  // m-tiles per row = 8
constexpr int NSLOT = 1024; // partial-reduction slots for PairNorm stats

__device__ __forceinline__ float4 ld4(const float* p){ return *reinterpret_cast<const float4*>(p); }
__device__ __forceinline__ float2 ld2(const float* p){ return *reinterpret_cast<const float2*>(p); }
__device__ __forceinline__ void st4(float* p, float4 v){ *reinterpret_cast<float4*>(p) = v; }

// ---------------- sq norms of pos ----------------
__global__ __launch_bounds__(256) void k_sq_pos(const float* __restrict__ x, float* __restrict__ sq){
  int i = blockIdx.x*256 + threadIdx.x;
  float2 v = ld2(x + (size_t)2*i);
  sq[i] = v.x*v.x + v.y*v.y;
}

// ---------------- pre-transpose W into WT[n][k] (n in [0,2*DOUT)) ----------------
template<int DIN, int DOUT>
__global__ void k_wt(const float* __restrict__ W, float* __restrict__ WT){
  int n = blockIdx.x, k = threadIdx.x;
  float v = (n < DOUT) ? W[(size_t)k*DOUT + n]
                       : W[(size_t)DIN*DOUT + (size_t)k*DOUT + (n - DOUT)];
  WT[(size_t)n*DIN + k] = v;
}

// ---------------- per-tile top-NK selection epilogue (row-interleaved) ----------------
// Lex (v, col), strict < == lax.top_k lowest-index tie-break. 8 rows interleaved
// per shuffle step (8x ILP); lane rx==sel banks winners; one 80B write/row at end.
// Round-13 lesson: symmetric both-direction selection cost more than it saved
// (VGPR 68->96, occupancy 30->16.6%). Round-15 lesson: fusing the 80->10 merge
// into consumers cut merge parallelism 8x and regressed. Keep this exact split.
__device__ __forceinline__ void sel_rows(float (&d)[8][8], int rx, int m0, float2* c0){
  float kv[8]; int kc[8];
#pragma unroll
  for (int k=0;k<8;++k){ kv[k] = 0.f; kc[k] = 0; }
#pragma unroll 1
  for (int sel=0; sel<NK; ++sel){
    float v[8]; int c[8];
#pragma unroll
    for (int k=0;k<8;++k){
      v[k] = d[k][0]; c[k] = rx*8;
#pragma unroll
      for (int l=1;l<8;++l){
        int cc = rx*8+l;
        if (d[k][l] < v[k]){ v[k] = d[k][l]; c[k] = cc; }
      }
    }
#pragma unroll
    for (int off=1; off<16; off<<=1){
#pragma unroll
      for (int k=0;k<8;++k){
        float ov = __shfl_xor(v[k], off, 64);
        int   oc = __shfl_xor(c[k], off, 64);
        if (ov < v[k] || (ov == v[k] && oc < c[k])){ v[k] = ov; c[k] = oc; }
      }
    }
#pragma unroll
    for (int k=0;k<8;++k){
      if (rx == (c[k]>>3)){
#pragma unroll
        for (int l=0;l<8;++l) if (l == (c[k]&7)) d[k][l] = __builtin_inff();
      }
    }
    if (rx == sel){
#pragma unroll
      for (int k=0;k<8;++k){ kv[k] = v[k]; kc[k] = c[k]; }
    }
  }
  if (rx < NK){
#pragma unroll
    for (int k=0;k<8;++k)
      c0[(size_t)k*(NT*NK) + rx] = make_float2(kv[k], (float)(m0 + kc[k]));
  }
}

// ---------------- fused kNN, DIN=2 (layer 1) ----------------
__global__ __launch_bounds__(256) void k_knn2(const float* __restrict__ x,
    const float* __restrict__ sq, float2* __restrict__ cand){
  int b = blockIdx.z;
  int n0 = blockIdx.x*128, m0 = blockIdx.y*128;
  int ry = threadIdx.x>>4, rx = threadIdx.x&15;
  const float* xb = x + (size_t)b*NP*2;
  const float* sqb = sq + (size_t)b*NP;
  float2 av[8], bv[8]; float sn[8], sm[8];
#pragma unroll
  for (int k=0;k<8;++k){
    av[k] = ld2(xb + (size_t)(n0+ry*8+k)*2);
    bv[k] = ld2(xb + (size_t)(m0+rx*8+k)*2);
    sn[k] = sqb[n0+ry*8+k];
    sm[k] = sqb[m0+rx*8+k];
  }
  float d[8][8];
#pragma unroll
  for (int k=0;k<8;++k)
#pragma unroll
    for (int l=0;l<8;++l){
      float dot = av[k].x*bv[l].x + av[k].y*bv[l].y;
      d[k][l] = (sn[k] + sm[l]) - 2.f*dot;
    }
  sel_rows(d, rx, m0, cand + (((size_t)b*NP + n0 + ry*8)*NT + blockIdx.y)*NK);
}

// ---------------- fused kNN, DIN in {64,128}: K4p=8 phased GEMM + select ----------------
// FIXED 32KB LDS (2 x 128 x 8 f4): DIN=64 -> 2 phases, DIN=128 -> 4 phases.
// 32KB -> 4-5 blocks/CU (round 12: occupancy 30%, VALUBusy 70%). 64KB was
// 2 waves/SIMD and latency-bound (round 11: 306us). Rolled staging (lean
// idiom); register staging spilled in rounds 5-8 -- keep it rolled.
template<int DIN>
__global__ __launch_bounds__(256) void k_knn(const float* __restrict__ x,
    const float* __restrict__ sq, float2* __restrict__ cand){
  constexpr int K4 = DIN/4, K4p = 8, NPH = K4/K4p, MASK = K4p-1;
  extern __shared__ float4 smem[];
  float4* as4 = smem;            // 128*K4p
  float4* bs4 = smem + 128*K4p;  // 128*K4p
  int b = blockIdx.z;
  int n0 = blockIdx.x*128, m0 = blockIdx.y*128;
  int ry = threadIdx.x>>4, rx = threadIdx.x&15;
  const float* xb = x + (size_t)b*NP*DIN;
  float acc[8][8];
#pragma unroll
  for (int k=0;k<8;++k)
#pragma unroll
    for (int l=0;l<8;++l) acc[k][l] = 0.f;
#pragma unroll 1
  for (int ph=0; ph<NPH; ++ph){
    __syncthreads();                       // previous phase reads done
    for (int u=threadIdx.x; u<128*K4p; u+=256){
      int r = u >> 3, c = u & 7;
      int sw = r*K4p + ((c + (r>>3)) & MASK);
      as4[sw] = ld4(xb + (size_t)(n0+r)*DIN + 4*(ph*K4p + c));
      bs4[sw] = ld4(xb + (size_t)(m0+r)*DIN + 4*(ph*K4p + c));
    }
    __syncthreads();                       // staged data visible
#pragma unroll 2
    for (int d4=0; d4<K4p; ++d4){
      float4 a_[8], b_[8];
#pragma unroll
      for (int k=0;k<8;++k) a_[k] = as4[(ry*8+k)*K4p + ((d4 + ry) & MASK)];
#pragma unroll
      for (int l=0;l<8;++l) b_[l] = bs4[(rx*8+l)*K4p + ((d4 + rx) & MASK)];
#pragma unroll
      for (int k=0;k<8;++k)
#pragma unroll
        for (int l=0;l<8;++l)
          acc[k][l] += a_[k].x*b_[l].x + a_[k].y*b_[l].y + a_[k].z*b_[l].z + a_[k].w*b_[l].w;
    }
  }
  const float* sqb = sq + (size_t)b*NP;
  float sn[8], sm[8];
#pragma unroll
  for (int k=0;k<8;++k){ sn[k] = sqb[n0+ry*8+k]; sm[k] = sqb[m0+rx*8+k]; }
#pragma unroll
  for (int k=0;k<8;++k)
#pragma unroll
    for (int l=0;l<8;++l) acc[k][l] = (sn[k]+sm[l]) - 2.f*acc[k][l];
  sel_rows(acc, rx, m0, cand + (((size_t)b*NP + n0 + ry*8)*NT + blockIdx.y)*NK);
}

// ---------------- merge per-tile candidates: 80 -> final NK indices ----------------
// Wave-per-row (8192 blocks x 4 waves): keep SEPARATE -- fusing into consumers
// (round 15) cut merge parallelism 8x and cost +94us.
__global__ __launch_bounds__(256) void k_merge(const float2* __restrict__ cand,
    int* __restrict__ idx){
  int wid = threadIdx.x>>6, lane = threadIdx.x&63;
  int row = blockIdx.x*4 + wid;
  const float2* cr = cand + (size_t)row*(NT*NK);
  float2 e0 = cr[lane];
  float v0 = e0.x; int c0 = (int)e0.y;
  float v1; int c1;
  if (lane < NT*NK - 64){ float2 e1 = cr[64+lane]; v1 = e1.x; c1 = (int)e1.y; }
  else { v1 = __builtin_inff(); c1 = 0x7fffffff; }
  int* out = idx + (size_t)row*NK;
  for (int sel=0; sel<NK; ++sel){
    float v; int c;
    if (v1 < v0 || (v1 == v0 && c1 < c0)){ v = v1; c = c1; } else { v = v0; c = c0; }
#pragma unroll
    for (int off=1; off<64; off<<=1){
      float ov = __shfl_xor(v, off, 64);
      int   oc = __shfl_xor(c, off, 64);
      if (ov < v || (ov == v && oc < c)){ v = ov; c = oc; }
    }
    if (c0 == c) v0 = __builtin_inff();
    if (c1 == c) v1 = __builtin_inff();
    if (lane == 0) out[sel] = c;
  }
}

// ---------------- GEMM: xcat = x @ WT^T, K4p=8 phases, pre-transposed W ----------------
template<int DIN, int DOUT>
__global__ __launch_bounds__(256) void k_gemm(const float* __restrict__ x,
    const float* __restrict__ WT, float* __restrict__ xcat, int m_base){
  constexpr int K4 = DIN/4, K4p = 8, NPH = K4/K4p, MASK = K4p-1;
  extern __shared__ float4 smem[];
  float4* as4 = smem;            // 128*K4p
  float4* bs4 = smem + 128*K4p;  // 128*K4p
  int m0 = blockIdx.x*128;                 // local row tile
  int nc = blockIdx.y*128;                 // output col tile in [0, 2*DOUT)
  const float* xg = x + (size_t)(m_base + m0)*DIN;
  const float* Bg = WT + (size_t)nc*DIN;
  int ry = threadIdx.x>>4, rx = threadIdx.x&15;
  float acc[8][8];
#pragma unroll
  for (int k=0;k<8;++k)
#pragma unroll
    for (int l=0;l<8;++l) acc[k][l] = 0.f;
#pragma unroll 1
  for (int ph=0; ph<NPH; ++ph){
    __syncthreads();
    for (int u=threadIdx.x; u<128*K4p; u+=256){
      int r = u >> 3, c = u & 7;
      int sw = r*K4p + ((c + (r>>3)) & MASK);
      as4[sw] = ld4(xg + (size_t)r*DIN + 4*(ph*K4p + c));
      bs4[sw] = ld4(Bg + (size_t)r*DIN + 4*(ph*K4p + c));
    }
    __syncthreads();
#pragma unroll 2
    for (int d4=0; d4<K4p; ++d4){
      float4 a_[8], b_[8];
#pragma unroll
      for (int k=0;k<8;++k) a_[k] = as4[(ry*8+k)*K4p + ((d4 + ry) & MASK)];
#pragma unroll
      for (int l=0;l<8;++l) b_[l] = bs4[(rx*8+l)*K4p + ((d4 + rx) & MASK)];
#pragma unroll
      for (int k=0;k<8;++k)
#pragma unroll
        for (int l=0;l<8;++l)
          acc[k][l] += a_[k].x*b_[l].x + a_[k].y*b_[l].y + a_[k].z*b_[l].z + a_[k].w*b_[l].w;
    }
  }
  float* outb = xcat + (size_t)(m0 + ry*8)*(2*DOUT) + nc + rx*8;
#pragma unroll
  for (int k=0;k<8;++k){
    st4(outb + (size_t)k*(2*DOUT),     make_float4(acc[k][0],acc[k][1],acc[k][2],acc[k][3]));
    st4(outb + (size_t)k*(2*DOUT) + 4, make_float4(acc[k][4],acc[k][5],acc[k][6],acc[k][7]));
  }
}

// ---------------- gather-max epilogue: h = relu(z + b - y_self + max_j y_j) ----------------
template<int DOUT>
__global__ __launch_bounds__(256) void k_gmax(const float* __restrict__ xcat,
    const int* __restrict__ idx, const float* __restrict__ bias,
    float* __restrict__ hout, float* __restrict__ spart, int p_base, int slot_base){
  constexpr int TP = DOUT/4;        // threads per point
  constexpr int ROWS = 256/TP;      // points in flight
  constexpr int PPT = 32/ROWS;      // points per thread
  __shared__ int idx_s[32*NK];
  __shared__ float red[1024];       // ROWS*DOUT == 1024 floats
  __shared__ float ssp[4];
  int c4 = threadIdx.x % TP, pr = threadIdx.x / TP;
  int c = 4*c4;
  int p0 = blockIdx.x*32 + p_base;          // global first point of block
  for (int t=threadIdx.x; t<32*NK; t+=256) idx_s[t] = idx[(size_t)p0*NK + t];
  __syncthreads();
  float4 b4 = ld4(bias + c);
  float4 fsum = make_float4(0.f,0.f,0.f,0.f);
  float ss = 0.f;
  int pbl = (((p0 - p_base) >> 10) << 10);  // local batch base row
#pragma unroll
  for (int t=0; t<PPT; ++t){
    int pl = pr + t*ROWS;
    int lrow = (p0 - p_base) + pl;
    const float* row = xcat + (size_t)lrow*(2*DOUT);
    float4 z = ld4(row + c), ys = ld4(row + DOUT + c);
    float4 mv = make_float4(-__builtin_inff(),-__builtin_inff(),-__builtin_inff(),-__builtin_inff());
    for (int j=0;j<NK;++j){
      int q = pbl + idx_s[pl*NK + j];
      float4 g = ld4(xcat + (size_t)q*(2*DOUT) + DOUT + c);
      mv.x = fmaxf(mv.x, g.x); mv.y = fmaxf(mv.y, g.y);
      mv.z = fmaxf(mv.z, g.z); mv.w = fmaxf(mv.w, g.w);
    }
    float4 v;
    v.x = fmaxf(z.x + b4.x - ys.x + mv.x, 0.f);
    v.y = fmaxf(z.y + b4.y - ys.y + mv.y, 0.f);
    v.z = fmaxf(z.z + b4.z - ys.z + mv.z, 0.f);
    v.w = fmaxf(z.w + b4.w - ys.w + mv.w, 0.f);
    st4(hout + (size_t)(p0 + pl)*DOUT + c, v);
    fsum.x += v.x; fsum.y += v.y; fsum.z += v.z; fsum.w += v.w;
    ss += v.x*v.x + v.y*v.y + v.z*v.z + v.w*v.w;
  }
  st4(&red[pr*DOUT + c], fsum);
#pragma unroll
  for (int off=32; off; off>>=1) ss += __shfl_xor(ss, off, 64);
  if ((threadIdx.x&63)==0) ssp[threadIdx.x>>6] = ss;
  __syncthreads();
  int slot = slot_base + blockIdx.x;
  for (int o=threadIdx.x; o<DOUT; o+=256){
    float s = 0.f;
#pragma unroll
    for (int r=0;r<ROWS;++r) s += red[r*DOUT + o];
    spart[(size_t)o*NSLOT + slot] = s;
  }
  if (threadIdx.x==0) spart[(size_t)DOUT*NSLOT + slot] = ssp[0]+ssp[1]+ssp[2]+ssp[3];
}

// ---------------- edge conv layer 1 (din=2, dout=64) ----------------
__global__ __launch_bounds__(256) void k_edge1(const float* __restrict__ x,
    const int* __restrict__ idx, const float* __restrict__ W,
    const float* __restrict__ bias, float* __restrict__ hout,
    float* __restrict__ spart){
  __shared__ int idx_s[32*NK];
  __shared__ float red[4][64];
  __shared__ float ssw[4];
  int lane = threadIdx.x & 63, wv = threadIdx.x >> 6;
  int p0 = blockIdx.x * 32;
  int b = p0 >> 10;
  int pl0 = p0 & 1023;
  const float* xb = x + ((size_t)b<<10)*2;
  for (int t=threadIdx.x; t<32*NK; t+=256) idx_s[t] = idx[(size_t)p0*NK + t];
  __syncthreads();
  float w0=W[lane], w1=W[64+lane], w2=W[128+lane], w3=W[192+lane];
  float bi = bias[lane];
  float fsum = 0.f, ss = 0.f;
#pragma unroll
  for (int t=0;t<8;++t){
    int pl = wv*8 + t;
    float2 xi = ld2(xb + (size_t)(pl0+pl)*2);
    float common = xi.x*w0 + xi.y*w1 + bi;
    float mv = -__builtin_inff();
    for (int j=0;j<NK;++j){
      float2 xj = ld2(xb + (size_t)idx_s[pl*NK+j]*2);
      mv = fmaxf(mv, (xj.x-xi.x)*w2 + (xj.y-xi.y)*w3);
    }
    float v = fmaxf(common + mv, 0.f);
    hout[(size_t)(p0+pl)*64 + lane] = v;
    fsum += v; ss += v*v;
  }
  red[wv][lane] = fsum;
#pragma unroll
  for (int off=32; off; off>>=1) ss += __shfl_xor(ss, off, 64);
  if (lane==0) ssw[wv] = ss;
  __syncthreads();
  if (threadIdx.x < 64){
    float s = red[0][lane]+red[1][lane]+red[2][lane]+red[3][lane];
    spart[(size_t)lane*NSLOT + blockIdx.x] = s;
  }
  if (threadIdx.x==0) spart[(size_t)64*NSLOT + blockIdx.x] = ssw[0]+ssw[1]+ssw[2]+ssw[3];
}

// ---------------- finalize PairNorm stats from partials ----------------
template<int DOUT>
__global__ __launch_bounds__(256) void k_finalize2(const float* __restrict__ spart,
    float* __restrict__ stats){
  __shared__ float part[4];
  __shared__ float ssh;
  float musq = 0.f;
  for (int f = threadIdx.x; f <= DOUT; f += 256){
    const float* row = spart + (size_t)f*NSLOT;
    float4 a = make_float4(0.f,0.f,0.f,0.f);
    for (int s=0; s<NSLOT; s+=4){
      float4 v = ld4(row + s);
      a.x += v.x; a.y += v.y; a.z += v.z; a.w += v.w;
    }
    float s = (a.x + a.y) + (a.z + a.w);
    if (f < DOUT){
      float m = s * (1.f/BN);
      stats[320+f] = m;
      musq += m*m;
    } else {
      ssh = s;
    }
  }
#pragma unroll
  for (int off=32; off; off>>=1) musq += __shfl_xor(musq, off, 64);
  if ((threadIdx.x&63)==0) part[threadIdx.x>>6] = musq;
  __syncthreads();
  if (threadIdx.x==0){
    float mu2 = part[0]+part[1]+part[2]+part[3];
    float msn = ssh*(1.f/BN) - mu2;
    stats[576] = 1.f / sqrtf(1e-5f + msn);
  }
}

// ---------------- normalize in place + next-layer sq (wave per row) ----------------
template<int DOUT>
__global__ __launch_bounds__(256) void k_norm(float* __restrict__ h,
    const float* __restrict__ stats, float* __restrict__ sq){
  int lane = threadIdx.x&63, wv = threadIdx.x>>6;
  int row = blockIdx.x*4 + wv;
  float inv = stats[576];
  const float* mu = stats + 320;
  float* hr = h + (size_t)row*DOUT;
  float s = 0.f;
  if constexpr (DOUT == 64){
    float v = (hr[lane] - mu[lane]) * inv;
    hr[lane] = v;
    s = v*v;
  } else if constexpr (DOUT == 128){
    float2 x2 = ld2(hr + 2*lane), m2 = ld2(mu + 2*lane);
    float a = (x2.x - m2.x)*inv, b = (x2.y - m2.y)*inv;
    *reinterpret_cast<float2*>(hr + 2*lane) = make_float2(a,b);
    s = a*a + b*b;
  } else {
    float4 x4 = ld4(hr + 4*lane), m4 = ld4(mu + 4*lane);
    float4 v;
    v.x = (x4.x-m4.x)*inv; v.y = (x4.y-m4.y)*inv;
    v.z = (x4.z-m4.z)*inv; v.w = (x4.w-m4.w)*inv;
    st4(hr + 4*lane, v);
    s = v.x*v.x + v.y*v.y + v.z*v.z + v.w*v.w;
  }
#pragma unroll
  for (int off=32; off; off>>=1) s += __shfl_xor(s, off, 64);
  if (lane==0) sq[row] = s;
}

// ---------------- global max pool (partial) ----------------
__global__ __launch_bounds__(256) void k_pool1(const float* __restrict__ h, float* __restrict__ gpart){
  int b = blockIdx.x, c = blockIdx.y, o = threadIdx.x;
  const float* hp = h + ((size_t)b*NP + c*128)*256 + o;
  float m = -__builtin_inff();
  for (int n=0;n<128;++n) m = fmaxf(m, hp[(size_t)n*256]);
  gpart[((size_t)c*NB + b)*256 + o] = m;
}

// ---------------- pool finish + MLP head ----------------
__global__ __launch_bounds__(256) void k_head(const float* __restrict__ gpart,
    const float* __restrict__ Wl1, const float* __restrict__ bl1,
    const float* __restrict__ Wl2, const float* __restrict__ bl2,
    float* __restrict__ out){
  __shared__ float g_s[256];
  __shared__ float h_s[64];
  int b = blockIdx.x, t = threadIdx.x;
  float m = -__builtin_inff();
  for (int c=0;c<8;++c) m = fmaxf(m, gpart[((size_t)c*NB + b)*256 + t]);
  g_s[t] = m;
  __syncthreads();
  if (t < 64){
    float a = bl1[t];
    for (int k=0;k<256;++k) a += g_s[k]*Wl1[(size_t)k*64 + t];
    h_s[t] = fmaxf(a, 0.f);
  }
  __syncthreads();
  if (t < 2){
    float a = bl2[t];
    for (int i=0;i<64;++i) a += h_s[i]*Wl2[(size_t)i*2 + t];
    out[(size_t)b*2 + t] = a;
  }
}

extern "C" void kernel_launch(void* const* d_in, const int* in_sizes, int n_in,
                              void* d_out, int out_size, void* d_ws, size_t ws_size,
                              hipStream_t stream){
  (void)in_sizes; (void)n_in; (void)out_size; (void)ws_size;
  const float* pos = (const float*)d_in[0];
  const float* W1  = (const float*)d_in[1];
  const float* b1  = (const float*)d_in[2];
  const float* W2  = (const float*)d_in[3];
  const float* b2  = (const float*)d_in[4];
  const float* W3  = (const float*)d_in[5];
  const float* b3  = (const float*)d_in[6];
  const float* Wl1 = (const float*)d_in[7];
  const float* bl1 = (const float*)d_in[8];
  const float* Wl2 = (const float*)d_in[9];
  const float* bl2 = (const float*)d_in[10];
  float* outp = (float*)d_out;

  (void)hipFuncSetAttribute((const void*)k_knn<128>,       hipFuncAttributeMaxDynamicSharedMemorySize, 32768);
  (void)hipFuncSetAttribute((const void*)k_knn<64>,        hipFuncAttributeMaxDynamicSharedMemorySize, 32768);
  (void)hipFuncSetAttribute((const void*)k_gemm<128,256>,  hipFuncAttributeMaxDynamicSharedMemorySize, 32768);
  (void)hipFuncSetAttribute((const void*)k_gemm<64,128>,   hipFuncAttributeMaxDynamicSharedMemorySize, 32768);

  char* w = (char*)d_ws;
  size_t off = 0;
  auto take = [&](size_t bytes)->char*{ char* p = w + off; off += (bytes + 255) & ~(size_t)255; return p; };
  float* sq    = (float*)take((size_t)BN*4);
  int*   idx   = (int*)  take((size_t)BN*NK*4);
  float* x1    = (float*)take((size_t)BN*64*4);
  float* x2    = (float*)take((size_t)BN*128*4);
  float* x3    = (float*)take((size_t)BN*256*4);
  float* stats = (float*)take(4096);
  float* spart = (float*)take((size_t)257*NSLOT*4);    // feature-major partials
  float* gpart = (float*)take((size_t)8*NB*256*4);
  float* wt2   = (float*)take((size_t)256*64*4);       // W2 pre-transposed [n][k]
  float* wt3   = (float*)take((size_t)512*128*4);      // W3 pre-transposed [n][k]
  float* big   = (float*)take((size_t)BN*(2*256)*4);   // 64MB: cand (21MB) then xcat, disjoint lifetimes
  float2* cand = (float2*)big;                         // BN * NT * NK float2
  float* xcat  = big;

  dim3 gknn(NP/128, NP/128, NB);

  // pre-transpose weights (tiny, once per call)
  k_wt<64,128><<<256, 64, 0, stream>>>(W2, wt2);
  k_wt<128,256><<<512, 128, 0, stream>>>(W3, wt3);

  // ---- layer 1 ----
  k_sq_pos<<<BN/256, 256, 0, stream>>>(pos, sq);
  k_knn2<<<gknn, 256, 0, stream>>>(pos, sq, cand);
  k_merge<<<BN/4, 256, 0, stream>>>(cand, idx);
  k_edge1<<<BN/32, 256, 0, stream>>>(pos, idx, W1, b1, x1, spart);
  k_finalize2<64><<<1, 256, 0, stream>>>(spart, stats);
  k_norm<64><<<BN/4, 256, 0, stream>>>(x1, stats, sq);

  // ---- layer 2 ----
  k_knn<64><<<gknn, 256, 32768, stream>>>(x1, sq, cand);
  k_merge<<<BN/4, 256, 0, stream>>>(cand, idx);
  k_gemm<64,128><<<dim3(BN/128, 2), 256, 32768, stream>>>(x1, wt2, xcat, 0);
  k_gmax<128><<<BN/32, 256, 0, stream>>>(xcat, idx, b2, x2, spart, 0, 0);
  k_finalize2<128><<<1, 256, 0, stream>>>(spart, stats);
  k_norm<128><<<BN/4, 256, 0, stream>>>(x2, stats, sq);

  // ---- layer 3 (single pass: big is 64MB) ----
  k_knn<128><<<gknn, 256, 32768, stream>>>(x2, sq, cand);
  k_merge<<<BN/4, 256, 0, stream>>>(cand, idx);
  k_gemm<128,256><<<dim3(BN/128, 4), 256, 32768, stream>>>(x2, wt3, xcat, 0);
  k_gmax<256><<<BN/32, 256, 0, stream>>>(xcat, idx, b3, x3, spart, 0, 0);
  k_finalize2<256><<<1, 256, 0, stream>>>(spart, stats);
  k_norm<256><<<BN/4, 256, 0, stream>>>(x3, stats, sq);

  // ---- pool + head ----
  k_pool1<<<dim3(NB, 8), 256, 0, stream>>>(x3, gpart);
  k_head<<<NB, 256, 0, stream>>>(gpart, Wl1, bl1, Wl2, bl2, outp);
}